// Round 14
// baseline (55.764 us; speedup 1.0000x reference)
//
#include <hip/hip_runtime.h>
#include <math.h>

#define BB 4
#define LL 256
#define TT 256
#define DD 512

// e^{2x} = exp2(x * 2/ln2)
#define EXP2K 2.885390081777927f

using short8 = __attribute__((ext_vector_type(8))) short;
using f32x4  = __attribute__((ext_vector_type(4))) float;

__device__ __forceinline__ unsigned cvt2bf(float a, float b) {
  unsigned r;
  asm("v_cvt_pk_bf16_f32 %0, %1, %2" : "=v"(r) : "v"(a), "v"(b));
  return r;  // lo = bf16(a), hi = bf16(b)
}

// ---------------------------------------------------------------------------
// Kernel 1: combined projection GEMM via bf16 MFMA, fp32 accumulate (R8-proven).
// Rows 0..1023:   E1  = exp(2*(x@W1^T+b1))   f32 row-major [B*L, D]
// Rows 1024..2047: E2c = exp(2*(mem@W2^T+b2)) f32 CHUNKED [d>>2][b*T+t][d&3]
// ---------------------------------------------------------------------------
__global__ __launch_bounds__(256) void proj_gemm(
    const float* __restrict__ x, const float* __restrict__ mem,
    const float* __restrict__ W1, const float* __restrict__ b1,
    const float* __restrict__ W2, const float* __restrict__ b2,
    float* __restrict__ E1, float* __restrict__ E2c)
{
  __shared__ __align__(16) char Abuf[32 * 144];   // 32 rows x 64 bf16 (+pad)
  __shared__ __align__(16) char Bbuf[64 * 144];   // 64 cols x 64 bf16 (+pad)

  const int tid = threadIdx.x;
  const int m0 = blockIdx.x * 32;      // 0..2047 in steps of 32
  const int n0 = blockIdx.y * 64;      // 0..511  in steps of 64
  const bool second = (m0 >= BB * LL);

  const float* A    = second ? mem + (size_t)(m0 - BB * LL) * DD
                             : x   + (size_t)m0 * DD;
  const float* W    = second ? W2 : W1;
  const float* bias = second ? b2 : b1;

  const int srow = tid >> 4;           // 0..15 staging row
  const int kq   = (tid & 15) * 4;     // k quad within 64

  const int lane = tid & 63;
  const int wid  = tid >> 6;
  const int r0   = (wid & 1) * 16;
  const int n0w  = (wid >> 1) * 32;
  const int lr   = lane & 15;
  const int lg   = lane >> 4;

  const int aoff  = (r0 + lr) * 144 + lg * 16;
  const int boff0 = (n0w + lr) * 144 + lg * 16;
  const int boff1 = (n0w + 16 + lr) * 144 + lg * 16;

  f32x4 acc0 = {0.f, 0.f, 0.f, 0.f};
  f32x4 acc1 = {0.f, 0.f, 0.f, 0.f};

  for (int kc = 0; kc < DD; kc += 64) {
    __syncthreads();
#pragma unroll
    for (int p = 0; p < 2; ++p) {      // A: 32 rows
      const int r = srow + p * 16;
      float4 v = *(const float4*)(A + (size_t)r * DD + kc + kq);
      uint2 u = {cvt2bf(v.x, v.y), cvt2bf(v.z, v.w)};
      *(uint2*)(Abuf + r * 144 + kq * 2) = u;
    }
#pragma unroll
    for (int p = 0; p < 4; ++p) {      // B: 64 rows (= n cols)
      const int r = srow + p * 16;
      float4 v = *(const float4*)(W + (size_t)(n0 + r) * DD + kc + kq);
      uint2 u = {cvt2bf(v.x, v.y), cvt2bf(v.z, v.w)};
      *(uint2*)(Bbuf + r * 144 + kq * 2) = u;
    }
    __syncthreads();
#pragma unroll
    for (int ks = 0; ks < 2; ++ks) {
      short8 af  = *(const short8*)(Abuf + aoff  + ks * 64);
      short8 bf0 = *(const short8*)(Bbuf + boff0 + ks * 64);
      short8 bf1 = *(const short8*)(Bbuf + boff1 + ks * 64);
      acc0 = __builtin_amdgcn_mfma_f32_16x16x32_bf16(af, bf0, acc0, 0, 0, 0);
      acc1 = __builtin_amdgcn_mfma_f32_16x16x32_bf16(af, bf1, acc1, 0, 0, 0);
    }
  }

  // epilogue: C layout col=lane&15, row=(lane>>4)*4+i
#pragma unroll
  for (int nf = 0; nf < 2; ++nf) {
    const f32x4 a = nf ? acc1 : acc0;
    const int col = n0 + n0w + nf * 16 + lr;
    const float bv = bias[col];
#pragma unroll
    for (int i = 0; i < 4; ++i) {
      const int mrow = m0 + r0 + lg * 4 + i;
      const float val = exp2f((a[i] + bv) * EXP2K);
      if (!second) {
        E1[(size_t)mrow * DD + col] = val;
      } else {
        const int m2 = mrow - BB * LL;
        E2c[((size_t)(col >> 2) * (BB * TT) + m2) * 4 + (col & 3)] = val;
      }
    }
  }
}

// ---------------------------------------------------------------------------
// Kernel 2: FUSED score + softmax + PV — 1024 threads (16 waves, d-16ths).
// 512 blocks x 16 waves = 2 blocks/CU -> 32 waves/CU = 8 waves/SIMD (HW max);
// R12->R13 showed latency-bound behavior responding ~linearly to waves/SIMD.
// Block (b, lp) owns rows r0=lp, r1=255-lp: exactly 5 balanced 64-t-tiles.
// tanh(q+v) = 1 - 2/(Eq*Ev+1); S = -2*sum w/(Eq*Ev+1) (const drops in
// softmax). Per tile: 16 waves x 32-d-16th (scalar q/w loads, 8 coalesced
// float4 vector loads each), LDS cross-16th reduce (double-buffered).
// PV: waves 0-7 -> row0 (d-col = tid), waves 8-15 -> row1 (d-col = tid-512).
// ---------------------------------------------------------------------------
__global__ __launch_bounds__(1024, 8) void fused_attn(
    const float* __restrict__ E1, const float* __restrict__ E2c,
    const float* __restrict__ wt, const float* __restrict__ mem,
    const int* __restrict__ mask, float* __restrict__ out)
{
  __shared__ float prt[2][16][64];         // (buf, d-16th, t-lane)  8 KB
  __shared__ float S[2][TT];               // raw scores per row     2 KB
  __shared__ __align__(8) float Pt[TT][2]; // probabilities          2 KB
  __shared__ float rinvS[2];

  const int tid = threadIdx.x;             // 0..1023
  const int tl  = tid & 63;
  const int wv  = tid >> 6;                // 0..15
  const int dq  = __builtin_amdgcn_readfirstlane(wv);  // wave-uniform 16th

  const int lp = blockIdx.x;        // 0..127
  const int b  = blockIdx.y;
  const int r0 = lp;
  const int r1 = 255 - lp;
  const int tc0 = r0 >> 6;
  const int tc1 = r1 >> 6;
  const int c0  = 4 - tc0;          // tiles for row0 (c0 + tiles_r1 == 5)

  const size_t strE2 = (size_t)(BB * TT);  // float4 stride per d4 plane
  const float4* wp = (const float4*)wt + dq * 8;

  // ---- score phase: 5 balanced tiles ----
  for (int it = 0; it < 5; ++it) {
    const int isr1 = (it >= c0);
    const int row  = isr1 ? r1 : r0;
    const int tc   = isr1 ? (tc1 + it - c0) : (tc0 + it);
    const int t    = tc * 64 + tl;

    const float4* qp = (const float4*)(E1 + (size_t)(b * LL + row) * DD) + dq * 8;
    const float4* vp = (const float4*)E2c + (size_t)(dq * 8) * strE2 + (b * TT + t);

    float a0 = 0.f, a1 = 0.f, a2 = 0.f, a3 = 0.f;
#pragma unroll 8
    for (int j = 0; j < 8; ++j) {
      float4 vv = vp[(size_t)j * strE2];
      float4 q  = qp[j];
      float4 w  = wp[j];
      a0 = fmaf(w.x, __builtin_amdgcn_rcpf(fmaf(q.x, vv.x, 1.0f)), a0);
      a1 = fmaf(w.y, __builtin_amdgcn_rcpf(fmaf(q.y, vv.y, 1.0f)), a1);
      a2 = fmaf(w.z, __builtin_amdgcn_rcpf(fmaf(q.z, vv.z, 1.0f)), a2);
      a3 = fmaf(w.w, __builtin_amdgcn_rcpf(fmaf(q.w, vv.w, 1.0f)), a3);
    }
    prt[it & 1][dq][tl] = (a0 + a1) + (a2 + a3);
    __syncthreads();
    if (tid < 64) {
      const float* pp = &prt[it & 1][0][0];
      float s = 0.f;
#pragma unroll
      for (int q16 = 0; q16 < 16; ++q16) s += pp[q16 * 64 + tid];
      S[isr1][tc * 64 + tid] = s;
    }
  }
  __syncthreads();

  // ---- softmax: wave 0 -> r0, wave 1 -> r1 ----
  if (wv < 2) {
    const int row = wv ? r1 : r0;
    const int tb = tl * 4;
    float4 h = *(const float4*)(&S[wv][tb]);
    const int4 mk = *(const int4*)(mask + b * TT + tb);
    float v0 = (tb + 0 >= row && mk.x != 0) ? -2.0f * h.x : -1e30f;
    float v1 = (tb + 1 >= row && mk.y != 0) ? -2.0f * h.y : -1e30f;
    float v2 = (tb + 2 >= row && mk.z != 0) ? -2.0f * h.z : -1e30f;
    float v3 = (tb + 3 >= row && mk.w != 0) ? -2.0f * h.w : -1e30f;
    float mx = fmaxf(fmaxf(v0, v1), fmaxf(v2, v3));
#pragma unroll
    for (int o = 1; o < 64; o <<= 1) mx = fmaxf(mx, __shfl_xor(mx, o));
    float e0 = __expf(v0 - mx), e1 = __expf(v1 - mx),
          e2 = __expf(v2 - mx), e3 = __expf(v3 - mx);
    Pt[tb + 0][wv] = e0; Pt[tb + 1][wv] = e1;
    Pt[tb + 2][wv] = e2; Pt[tb + 3][wv] = e3;
    float sm = (e0 + e1) + (e2 + e3);
#pragma unroll
    for (int o = 1; o < 64; o <<= 1) sm += __shfl_xor(sm, o);
    if (tl == 0) rinvS[wv] = 1.0f / sm;
  }
  __syncthreads();

  // ---- PV: waves 0-7 -> row0, waves 8-15 -> row1 (1 d-col each) ----
  const int isrow1 = (tid >= 512);
  const int dd  = tid & 511;
  const int row = isrow1 ? r1 : r0;
  const float* mp = mem + ((size_t)b * TT) * DD + dd;
  float ax = 0.f;
  for (int t = row; t < TT; ++t) {
    ax = fmaf(Pt[t][isrow1], mp[(size_t)t * DD], ax);
  }
  out[((size_t)(b * LL + row)) * DD + dd] = ax * rinvS[isrow1];
}

extern "C" void kernel_launch(void* const* d_in, const int* in_sizes, int n_in,
                              void* d_out, int out_size, void* d_ws, size_t ws_size,
                              hipStream_t stream) {
  const float* x   = (const float*)d_in[0];
  const float* mem = (const float*)d_in[1];
  const float* W1  = (const float*)d_in[2];
  const float* b1  = (const float*)d_in[3];
  const float* W2  = (const float*)d_in[4];
  const float* b2  = (const float*)d_in[5];
  const float* wt  = (const float*)d_in[6];
  const int* mask  = (const int*)d_in[8];
  float* outp = (float*)d_out;

  float* E1  = (float*)d_ws;                     // [B*L, D]        2 MB
  float* E2c = E1 + (size_t)BB * LL * DD;        // [D/4][B*T][4]   2 MB (4 MB)

  proj_gemm<<<dim3((BB * LL + BB * TT) / 32, DD / 64), 256, 0, stream>>>(
      x, mem, W1, b1, W2, b2, E1, E2c);
  fused_attn<<<dim3(LL / 2, BB), 1024, 0, stream>>>(
      E1, E2c, wt, mem, mask, outp);
}

// Round 15
// 40.911 us; speedup vs baseline: 1.3631x; 1.3631x over previous
//
#include <hip/hip_runtime.h>
#include <math.h>

#define BB 4
#define LL 256
#define TT 256
#define DD 512

// e^{2x} = exp2(x * 2/ln2)
#define EXP2K 2.885390081777927f

using short8 = __attribute__((ext_vector_type(8))) short;
using f32x4  = __attribute__((ext_vector_type(4))) float;

__device__ __forceinline__ unsigned cvt2bf(float a, float b) {
  unsigned r;
  asm("v_cvt_pk_bf16_f32 %0, %1, %2" : "=v"(r) : "v"(a), "v"(b));
  return r;  // lo = bf16(a), hi = bf16(b)
}

// ---------------------------------------------------------------------------
// Kernel 1: combined projection GEMM via bf16 MFMA, fp32 accumulate (R8-proven).
// Rows 0..1023:   E1  = exp(2*(x@W1^T+b1))   f32 row-major [B*L, D]
// Rows 1024..2047: E2c = exp(2*(mem@W2^T+b2)) f32 CHUNKED [d>>2][b*T+t][d&3]
// ---------------------------------------------------------------------------
__global__ __launch_bounds__(256) void proj_gemm(
    const float* __restrict__ x, const float* __restrict__ mem,
    const float* __restrict__ W1, const float* __restrict__ b1,
    const float* __restrict__ W2, const float* __restrict__ b2,
    float* __restrict__ E1, float* __restrict__ E2c)
{
  __shared__ __align__(16) char Abuf[32 * 144];   // 32 rows x 64 bf16 (+pad)
  __shared__ __align__(16) char Bbuf[64 * 144];   // 64 cols x 64 bf16 (+pad)

  const int tid = threadIdx.x;
  const int m0 = blockIdx.x * 32;      // 0..2047 in steps of 32
  const int n0 = blockIdx.y * 64;      // 0..511  in steps of 64
  const bool second = (m0 >= BB * LL);

  const float* A    = second ? mem + (size_t)(m0 - BB * LL) * DD
                             : x   + (size_t)m0 * DD;
  const float* W    = second ? W2 : W1;
  const float* bias = second ? b2 : b1;

  const int srow = tid >> 4;           // 0..15 staging row
  const int kq   = (tid & 15) * 4;     // k quad within 64

  const int lane = tid & 63;
  const int wid  = tid >> 6;
  const int r0   = (wid & 1) * 16;
  const int n0w  = (wid >> 1) * 32;
  const int lr   = lane & 15;
  const int lg   = lane >> 4;

  const int aoff  = (r0 + lr) * 144 + lg * 16;
  const int boff0 = (n0w + lr) * 144 + lg * 16;
  const int boff1 = (n0w + 16 + lr) * 144 + lg * 16;

  f32x4 acc0 = {0.f, 0.f, 0.f, 0.f};
  f32x4 acc1 = {0.f, 0.f, 0.f, 0.f};

  for (int kc = 0; kc < DD; kc += 64) {
    __syncthreads();
#pragma unroll
    for (int p = 0; p < 2; ++p) {      // A: 32 rows
      const int r = srow + p * 16;
      float4 v = *(const float4*)(A + (size_t)r * DD + kc + kq);
      uint2 u = {cvt2bf(v.x, v.y), cvt2bf(v.z, v.w)};
      *(uint2*)(Abuf + r * 144 + kq * 2) = u;
    }
#pragma unroll
    for (int p = 0; p < 4; ++p) {      // B: 64 rows (= n cols)
      const int r = srow + p * 16;
      float4 v = *(const float4*)(W + (size_t)(n0 + r) * DD + kc + kq);
      uint2 u = {cvt2bf(v.x, v.y), cvt2bf(v.z, v.w)};
      *(uint2*)(Bbuf + r * 144 + kq * 2) = u;
    }
    __syncthreads();
#pragma unroll
    for (int ks = 0; ks < 2; ++ks) {
      short8 af  = *(const short8*)(Abuf + aoff  + ks * 64);
      short8 bf0 = *(const short8*)(Bbuf + boff0 + ks * 64);
      short8 bf1 = *(const short8*)(Bbuf + boff1 + ks * 64);
      acc0 = __builtin_amdgcn_mfma_f32_16x16x32_bf16(af, bf0, acc0, 0, 0, 0);
      acc1 = __builtin_amdgcn_mfma_f32_16x16x32_bf16(af, bf1, acc1, 0, 0, 0);
    }
  }

  // epilogue: C layout col=lane&15, row=(lane>>4)*4+i
#pragma unroll
  for (int nf = 0; nf < 2; ++nf) {
    const f32x4 a = nf ? acc1 : acc0;
    const int col = n0 + n0w + nf * 16 + lr;
    const float bv = bias[col];
#pragma unroll
    for (int i = 0; i < 4; ++i) {
      const int mrow = m0 + r0 + lg * 4 + i;
      const float val = exp2f((a[i] + bv) * EXP2K);
      if (!second) {
        E1[(size_t)mrow * DD + col] = val;
      } else {
        const int m2 = mrow - BB * LL;
        E2c[((size_t)(col >> 2) * (BB * TT) + m2) * 4 + (col & 3)] = val;
      }
    }
  }
}

// ---------------------------------------------------------------------------
// Kernel 2: FUSED score + softmax + PV — 512 threads (R13-proven structure)
// + anti-diagonal TILE SHARING. Rows r0=lp, r1=255-lp overlap in tiles
// tc in [tc1,4): those tiles are loaded ONCE and feed BOTH rows (24 VALU
// per vv load instead of 12). Rounds tc = tc0..3 (3 or 4, vs 5 before);
// compute stays exactly 5 tile-units/block: 2*(4-tc1)+(tc1-tc0) == 5 for
// every lp. Loads -30%, barriers -30%. R14 lesson applied: no VGPR cap
// (launch_bounds(512) only) so the unroll-8 load batch stays in flight.
// tanh(q+v) = 1 - 2/(Eq*Ev+1); S = -2*sum w/(Eq*Ev+1) (const drops in
// softmax). 8 waves x 64-d-octant, scalar q/w loads, LDS reduce (dbuf).
// ---------------------------------------------------------------------------
__global__ __launch_bounds__(512) void fused_attn(
    const float* __restrict__ E1, const float* __restrict__ E2c,
    const float* __restrict__ wt, const float* __restrict__ mem,
    const int* __restrict__ mask, float* __restrict__ out)
{
  __shared__ float prt[2][2][8][64];       // (buf, row, d-octant, t-lane) 16KB
  __shared__ float S[2][TT];               // raw scores per row            2KB
  __shared__ __align__(8) float Pt[TT][2]; // probabilities                 2KB
  __shared__ float rinvS[2];

  const int tid = threadIdx.x;             // 0..511
  const int tl  = tid & 63;
  const int wv  = tid >> 6;                // 0..7
  const int dq  = __builtin_amdgcn_readfirstlane(wv);  // wave-uniform octant

  const int lp = blockIdx.x;        // 0..127
  const int b  = blockIdx.y;
  const int r0 = lp;
  const int r1 = 255 - lp;
  const int tc0 = r0 >> 6;          // 0 or 1
  const int tc1 = r1 >> 6;          // 2 or 3

  const size_t strE2 = (size_t)(BB * TT);  // float4 stride per d4 plane
  const float4* wp  = (const float4*)wt + dq * 16;
  const float4* q0p = (const float4*)(E1 + (size_t)(b * LL + r0) * DD) + dq * 16;
  const float4* q1p = (const float4*)(E1 + (size_t)(b * LL + r1) * DD) + dq * 16;

  // ---- score phase: rounds tc0..3; shared rounds feed both rows ----
  for (int tc = tc0; tc < 4; ++tc) {
    const int it = tc - tc0;
    const bool shr = (tc >= tc1);          // block-uniform
    const int t = tc * 64 + tl;
    const float4* vp = (const float4*)E2c + (size_t)(dq * 16) * strE2 + (b * TT + t);

    float a0 = 0.f, a1 = 0.f, a2 = 0.f, a3 = 0.f;
    float b0 = 0.f, b1 = 0.f, b2 = 0.f, b3 = 0.f;
    if (shr) {
#pragma unroll 8
      for (int j = 0; j < 16; ++j) {
        float4 vv = vp[(size_t)j * strE2];
        float4 q0 = q0p[j];
        float4 q1 = q1p[j];
        float4 w  = wp[j];
        a0 = fmaf(w.x, __builtin_amdgcn_rcpf(fmaf(q0.x, vv.x, 1.0f)), a0);
        a1 = fmaf(w.y, __builtin_amdgcn_rcpf(fmaf(q0.y, vv.y, 1.0f)), a1);
        a2 = fmaf(w.z, __builtin_amdgcn_rcpf(fmaf(q0.z, vv.z, 1.0f)), a2);
        a3 = fmaf(w.w, __builtin_amdgcn_rcpf(fmaf(q0.w, vv.w, 1.0f)), a3);
        b0 = fmaf(w.x, __builtin_amdgcn_rcpf(fmaf(q1.x, vv.x, 1.0f)), b0);
        b1 = fmaf(w.y, __builtin_amdgcn_rcpf(fmaf(q1.y, vv.y, 1.0f)), b1);
        b2 = fmaf(w.z, __builtin_amdgcn_rcpf(fmaf(q1.z, vv.z, 1.0f)), b2);
        b3 = fmaf(w.w, __builtin_amdgcn_rcpf(fmaf(q1.w, vv.w, 1.0f)), b3);
      }
    } else {
#pragma unroll 8
      for (int j = 0; j < 16; ++j) {
        float4 vv = vp[(size_t)j * strE2];
        float4 q0 = q0p[j];
        float4 w  = wp[j];
        a0 = fmaf(w.x, __builtin_amdgcn_rcpf(fmaf(q0.x, vv.x, 1.0f)), a0);
        a1 = fmaf(w.y, __builtin_amdgcn_rcpf(fmaf(q0.y, vv.y, 1.0f)), a1);
        a2 = fmaf(w.z, __builtin_amdgcn_rcpf(fmaf(q0.z, vv.z, 1.0f)), a2);
        a3 = fmaf(w.w, __builtin_amdgcn_rcpf(fmaf(q0.w, vv.w, 1.0f)), a3);
      }
    }
    prt[it & 1][0][dq][tl] = (a0 + a1) + (a2 + a3);
    if (shr) prt[it & 1][1][dq][tl] = (b0 + b1) + (b2 + b3);
    __syncthreads();
    if (tid < 128) {
      const int rr = tid >> 6;
      const int tt = tid & 63;
      if (rr == 0 || shr) {
        const float* pp = &prt[it & 1][rr][0][0];
        float s = 0.f;
#pragma unroll
        for (int oc = 0; oc < 8; ++oc) s += pp[oc * 64 + tt];
        S[rr][tc * 64 + tt] = s;
      }
    }
  }
  __syncthreads();

  // ---- softmax: wave 0 -> r0, wave 1 -> r1 ----
  if (wv < 2) {
    const int row = wv ? r1 : r0;
    const int tb = tl * 4;
    float4 h = *(const float4*)(&S[wv][tb]);
    const int4 mk = *(const int4*)(mask + b * TT + tb);
    float v0 = (tb + 0 >= row && mk.x != 0) ? -2.0f * h.x : -1e30f;
    float v1 = (tb + 1 >= row && mk.y != 0) ? -2.0f * h.y : -1e30f;
    float v2 = (tb + 2 >= row && mk.z != 0) ? -2.0f * h.z : -1e30f;
    float v3 = (tb + 3 >= row && mk.w != 0) ? -2.0f * h.w : -1e30f;
    float mx = fmaxf(fmaxf(v0, v1), fmaxf(v2, v3));
#pragma unroll
    for (int o = 1; o < 64; o <<= 1) mx = fmaxf(mx, __shfl_xor(mx, o));
    float e0 = __expf(v0 - mx), e1 = __expf(v1 - mx),
          e2 = __expf(v2 - mx), e3 = __expf(v3 - mx);
    Pt[tb + 0][wv] = e0; Pt[tb + 1][wv] = e1;
    Pt[tb + 2][wv] = e2; Pt[tb + 3][wv] = e3;
    float sm = (e0 + e1) + (e2 + e3);
#pragma unroll
    for (int o = 1; o < 64; o <<= 1) sm += __shfl_xor(sm, o);
    if (tl == 0) rinvS[wv] = 1.0f / sm;
  }
  __syncthreads();

  // ---- PV: 512 threads x 1 d-col; loop split at r1 ----
  const int dd = tid;
  const float* mp = mem + ((size_t)b * TT) * DD + dd;
  float ax0 = 0.f, ax1 = 0.f;
#pragma unroll 4
  for (int t = r0; t < r1; ++t) {          // row0 only
    ax0 = fmaf(Pt[t][0], mp[(size_t)t * DD], ax0);
  }
#pragma unroll 4
  for (int t = r1; t < TT; ++t) {          // both rows
    float2 p = *(const float2*)(&Pt[t][0]);
    const float mv = mp[(size_t)t * DD];
    ax0 = fmaf(p.x, mv, ax0);
    ax1 = fmaf(p.y, mv, ax1);
  }
  out[((size_t)(b * LL + r0)) * DD + dd] = ax0 * rinvS[0];
  out[((size_t)(b * LL + r1)) * DD + dd] = ax1 * rinvS[1];
}

extern "C" void kernel_launch(void* const* d_in, const int* in_sizes, int n_in,
                              void* d_out, int out_size, void* d_ws, size_t ws_size,
                              hipStream_t stream) {
  const float* x   = (const float*)d_in[0];
  const float* mem = (const float*)d_in[1];
  const float* W1  = (const float*)d_in[2];
  const float* b1  = (const float*)d_in[3];
  const float* W2  = (const float*)d_in[4];
  const float* b2  = (const float*)d_in[5];
  const float* wt  = (const float*)d_in[6];
  const int* mask  = (const int*)d_in[8];
  float* outp = (float*)d_out;

  float* E1  = (float*)d_ws;                     // [B*L, D]        2 MB
  float* E2c = E1 + (size_t)BB * LL * DD;        // [D/4][B*T][4]   2 MB (4 MB)

  proj_gemm<<<dim3((BB * LL + BB * TT) / 32, DD / 64), 256, 0, stream>>>(
      x, mem, W1, b1, W2, b2, E1, E2c);
  fused_attn<<<dim3(LL / 2, BB), 512, 0, stream>>>(
      E1, E2c, wt, mem, mask, outp);
}

// Round 16
// 40.581 us; speedup vs baseline: 1.3741x; 1.0081x over previous
//
#include <hip/hip_runtime.h>
#include <math.h>

#define BB 4
#define LL 256
#define TT 256
#define DD 512

// e^{2x} = exp2(x * 2/ln2)
#define EXP2K 2.885390081777927f

using short8 = __attribute__((ext_vector_type(8))) short;
using f32x4  = __attribute__((ext_vector_type(4))) float;

__device__ __forceinline__ unsigned cvt2bf(float a, float b) {
  unsigned r;
  asm("v_cvt_pk_bf16_f32 %0, %1, %2" : "=v"(r) : "v"(a), "v"(b));
  return r;  // lo = bf16(a), hi = bf16(b)
}

// ---------------------------------------------------------------------------
// Kernel 1: combined projection GEMM via bf16 MFMA, fp32 accumulate (R8-proven).
// Rows 0..1023:   E1  = exp(2*(x@W1^T+b1))   f32 row-major [B*L, D]
// Rows 1024..2047: E2c = exp(2*(mem@W2^T+b2)) f32 CHUNKED [d>>2][b*T+t][d&3]
// ---------------------------------------------------------------------------
__global__ __launch_bounds__(256) void proj_gemm(
    const float* __restrict__ x, const float* __restrict__ mem,
    const float* __restrict__ W1, const float* __restrict__ b1,
    const float* __restrict__ W2, const float* __restrict__ b2,
    float* __restrict__ E1, float* __restrict__ E2c)
{
  __shared__ __align__(16) char Abuf[32 * 144];   // 32 rows x 64 bf16 (+pad)
  __shared__ __align__(16) char Bbuf[64 * 144];   // 64 cols x 64 bf16 (+pad)

  const int tid = threadIdx.x;
  const int m0 = blockIdx.x * 32;      // 0..2047 in steps of 32
  const int n0 = blockIdx.y * 64;      // 0..511  in steps of 64
  const bool second = (m0 >= BB * LL);

  const float* A    = second ? mem + (size_t)(m0 - BB * LL) * DD
                             : x   + (size_t)m0 * DD;
  const float* W    = second ? W2 : W1;
  const float* bias = second ? b2 : b1;

  const int srow = tid >> 4;           // 0..15 staging row
  const int kq   = (tid & 15) * 4;     // k quad within 64

  const int lane = tid & 63;
  const int wid  = tid >> 6;
  const int r0   = (wid & 1) * 16;
  const int n0w  = (wid >> 1) * 32;
  const int lr   = lane & 15;
  const int lg   = lane >> 4;

  const int aoff  = (r0 + lr) * 144 + lg * 16;
  const int boff0 = (n0w + lr) * 144 + lg * 16;
  const int boff1 = (n0w + 16 + lr) * 144 + lg * 16;

  f32x4 acc0 = {0.f, 0.f, 0.f, 0.f};
  f32x4 acc1 = {0.f, 0.f, 0.f, 0.f};

  for (int kc = 0; kc < DD; kc += 64) {
    __syncthreads();
#pragma unroll
    for (int p = 0; p < 2; ++p) {      // A: 32 rows
      const int r = srow + p * 16;
      float4 v = *(const float4*)(A + (size_t)r * DD + kc + kq);
      uint2 u = {cvt2bf(v.x, v.y), cvt2bf(v.z, v.w)};
      *(uint2*)(Abuf + r * 144 + kq * 2) = u;
    }
#pragma unroll
    for (int p = 0; p < 4; ++p) {      // B: 64 rows (= n cols)
      const int r = srow + p * 16;
      float4 v = *(const float4*)(W + (size_t)(n0 + r) * DD + kc + kq);
      uint2 u = {cvt2bf(v.x, v.y), cvt2bf(v.z, v.w)};
      *(uint2*)(Bbuf + r * 144 + kq * 2) = u;
    }
    __syncthreads();
#pragma unroll
    for (int ks = 0; ks < 2; ++ks) {
      short8 af  = *(const short8*)(Abuf + aoff  + ks * 64);
      short8 bf0 = *(const short8*)(Bbuf + boff0 + ks * 64);
      short8 bf1 = *(const short8*)(Bbuf + boff1 + ks * 64);
      acc0 = __builtin_amdgcn_mfma_f32_16x16x32_bf16(af, bf0, acc0, 0, 0, 0);
      acc1 = __builtin_amdgcn_mfma_f32_16x16x32_bf16(af, bf1, acc1, 0, 0, 0);
    }
  }

  // epilogue: C layout col=lane&15, row=(lane>>4)*4+i
#pragma unroll
  for (int nf = 0; nf < 2; ++nf) {
    const f32x4 a = nf ? acc1 : acc0;
    const int col = n0 + n0w + nf * 16 + lr;
    const float bv = bias[col];
#pragma unroll
    for (int i = 0; i < 4; ++i) {
      const int mrow = m0 + r0 + lg * 4 + i;
      const float val = exp2f((a[i] + bv) * EXP2K);
      if (!second) {
        E1[(size_t)mrow * DD + col] = val;
      } else {
        const int m2 = mrow - BB * LL;
        E2c[((size_t)(col >> 2) * (BB * TT) + m2) * 4 + (col & 3)] = val;
      }
    }
  }
}

// ---------------------------------------------------------------------------
// Kernel 2: FUSED score + softmax + PV — R15 body + XCD-AFFINITY SWIZZLE.
// blockIdx.x % 8 maps to XCD (round-robin, measured). Decode pins batch b to
// XCDs {2b, 2b+1}: per-XCD working set = ONE batch's E2c+mem (2.5 MB) < 4 MB
// L2, instead of all 4 batches (10 MB, thrashing -> L3 round trips).
//   k = bid & 7; b = k >> 1; lp = (bid >> 3) + ((k & 1) << 6)
// Rows r0=lp, r1=255-lp share anti-diagonal tiles (tc >= tc1 feed both rows
// from one vv load). tanh(q+v) = 1 - 2/(Eq*Ev+1); S = -2*sum w/(Eq*Ev+1).
// 8 waves x 64-d-octant, scalar q/w loads, LDS reduce (dbuf), no VGPR cap.
// ---------------------------------------------------------------------------
__global__ __launch_bounds__(512) void fused_attn(
    const float* __restrict__ E1, const float* __restrict__ E2c,
    const float* __restrict__ wt, const float* __restrict__ mem,
    const int* __restrict__ mask, float* __restrict__ out)
{
  __shared__ float prt[2][2][8][64];       // (buf, row, d-octant, t-lane) 16KB
  __shared__ float S[2][TT];               // raw scores per row            2KB
  __shared__ __align__(8) float Pt[TT][2]; // probabilities                 2KB
  __shared__ float rinvS[2];

  const int tid = threadIdx.x;             // 0..511
  const int tl  = tid & 63;
  const int wv  = tid >> 6;                // 0..7
  const int dq  = __builtin_amdgcn_readfirstlane(wv);  // wave-uniform octant

  // XCD-affinity decode (bid%8 = XCD on MI355X round-robin dispatch)
  const int bid = blockIdx.x;              // 0..511
  const int k   = bid & 7;
  const int b   = k >> 1;
  const int lp  = (bid >> 3) + ((k & 1) << 6);   // 0..127

  const int r0 = lp;
  const int r1 = 255 - lp;
  const int tc0 = r0 >> 6;          // 0 or 1
  const int tc1 = r1 >> 6;          // 2 or 3

  const size_t strE2 = (size_t)(BB * TT);  // float4 stride per d4 plane
  const float4* wp  = (const float4*)wt + dq * 16;
  const float4* q0p = (const float4*)(E1 + (size_t)(b * LL + r0) * DD) + dq * 16;
  const float4* q1p = (const float4*)(E1 + (size_t)(b * LL + r1) * DD) + dq * 16;

  // ---- score phase: rounds tc0..3; shared rounds feed both rows ----
  for (int tc = tc0; tc < 4; ++tc) {
    const int it = tc - tc0;
    const bool shr = (tc >= tc1);          // block-uniform
    const int t = tc * 64 + tl;
    const float4* vp = (const float4*)E2c + (size_t)(dq * 16) * strE2 + (b * TT + t);

    float a0 = 0.f, a1 = 0.f, a2 = 0.f, a3 = 0.f;
    float b0 = 0.f, b1 = 0.f, b2 = 0.f, b3 = 0.f;
    if (shr) {
#pragma unroll 8
      for (int j = 0; j < 16; ++j) {
        float4 vv = vp[(size_t)j * strE2];
        float4 q0 = q0p[j];
        float4 q1 = q1p[j];
        float4 w  = wp[j];
        a0 = fmaf(w.x, __builtin_amdgcn_rcpf(fmaf(q0.x, vv.x, 1.0f)), a0);
        a1 = fmaf(w.y, __builtin_amdgcn_rcpf(fmaf(q0.y, vv.y, 1.0f)), a1);
        a2 = fmaf(w.z, __builtin_amdgcn_rcpf(fmaf(q0.z, vv.z, 1.0f)), a2);
        a3 = fmaf(w.w, __builtin_amdgcn_rcpf(fmaf(q0.w, vv.w, 1.0f)), a3);
        b0 = fmaf(w.x, __builtin_amdgcn_rcpf(fmaf(q1.x, vv.x, 1.0f)), b0);
        b1 = fmaf(w.y, __builtin_amdgcn_rcpf(fmaf(q1.y, vv.y, 1.0f)), b1);
        b2 = fmaf(w.z, __builtin_amdgcn_rcpf(fmaf(q1.z, vv.z, 1.0f)), b2);
        b3 = fmaf(w.w, __builtin_amdgcn_rcpf(fmaf(q1.w, vv.w, 1.0f)), b3);
      }
    } else {
#pragma unroll 8
      for (int j = 0; j < 16; ++j) {
        float4 vv = vp[(size_t)j * strE2];
        float4 q0 = q0p[j];
        float4 w  = wp[j];
        a0 = fmaf(w.x, __builtin_amdgcn_rcpf(fmaf(q0.x, vv.x, 1.0f)), a0);
        a1 = fmaf(w.y, __builtin_amdgcn_rcpf(fmaf(q0.y, vv.y, 1.0f)), a1);
        a2 = fmaf(w.z, __builtin_amdgcn_rcpf(fmaf(q0.z, vv.z, 1.0f)), a2);
        a3 = fmaf(w.w, __builtin_amdgcn_rcpf(fmaf(q0.w, vv.w, 1.0f)), a3);
      }
    }
    prt[it & 1][0][dq][tl] = (a0 + a1) + (a2 + a3);
    if (shr) prt[it & 1][1][dq][tl] = (b0 + b1) + (b2 + b3);
    __syncthreads();
    if (tid < 128) {
      const int rr = tid >> 6;
      const int tt = tid & 63;
      if (rr == 0 || shr) {
        const float* pp = &prt[it & 1][rr][0][0];
        float s = 0.f;
#pragma unroll
        for (int oc = 0; oc < 8; ++oc) s += pp[oc * 64 + tt];
        S[rr][tc * 64 + tt] = s;
      }
    }
  }
  __syncthreads();

  // ---- softmax: wave 0 -> r0, wave 1 -> r1 ----
  if (wv < 2) {
    const int row = wv ? r1 : r0;
    const int tb = tl * 4;
    float4 h = *(const float4*)(&S[wv][tb]);
    const int4 mk = *(const int4*)(mask + b * TT + tb);
    float v0 = (tb + 0 >= row && mk.x != 0) ? -2.0f * h.x : -1e30f;
    float v1 = (tb + 1 >= row && mk.y != 0) ? -2.0f * h.y : -1e30f;
    float v2 = (tb + 2 >= row && mk.z != 0) ? -2.0f * h.z : -1e30f;
    float v3 = (tb + 3 >= row && mk.w != 0) ? -2.0f * h.w : -1e30f;
    float mx = fmaxf(fmaxf(v0, v1), fmaxf(v2, v3));
#pragma unroll
    for (int o = 1; o < 64; o <<= 1) mx = fmaxf(mx, __shfl_xor(mx, o));
    float e0 = __expf(v0 - mx), e1 = __expf(v1 - mx),
          e2 = __expf(v2 - mx), e3 = __expf(v3 - mx);
    Pt[tb + 0][wv] = e0; Pt[tb + 1][wv] = e1;
    Pt[tb + 2][wv] = e2; Pt[tb + 3][wv] = e3;
    float sm = (e0 + e1) + (e2 + e3);
#pragma unroll
    for (int o = 1; o < 64; o <<= 1) sm += __shfl_xor(sm, o);
    if (tl == 0) rinvS[wv] = 1.0f / sm;
  }
  __syncthreads();

  // ---- PV: 512 threads x 1 d-col; loop split at r1 ----
  const int dd = tid;
  const float* mp = mem + ((size_t)b * TT) * DD + dd;
  float ax0 = 0.f, ax1 = 0.f;
#pragma unroll 4
  for (int t = r0; t < r1; ++t) {          // row0 only
    ax0 = fmaf(Pt[t][0], mp[(size_t)t * DD], ax0);
  }
#pragma unroll 4
  for (int t = r1; t < TT; ++t) {          // both rows
    float2 p = *(const float2*)(&Pt[t][0]);
    const float mv = mp[(size_t)t * DD];
    ax0 = fmaf(p.x, mv, ax0);
    ax1 = fmaf(p.y, mv, ax1);
  }
  out[((size_t)(b * LL + r0)) * DD + dd] = ax0 * rinvS[0];
  out[((size_t)(b * LL + r1)) * DD + dd] = ax1 * rinvS[1];
}

extern "C" void kernel_launch(void* const* d_in, const int* in_sizes, int n_in,
                              void* d_out, int out_size, void* d_ws, size_t ws_size,
                              hipStream_t stream) {
  const float* x   = (const float*)d_in[0];
  const float* mem = (const float*)d_in[1];
  const float* W1  = (const float*)d_in[2];
  const float* b1  = (const float*)d_in[3];
  const float* W2  = (const float*)d_in[4];
  const float* b2  = (const float*)d_in[5];
  const float* wt  = (const float*)d_in[6];
  const int* mask  = (const int*)d_in[8];
  float* outp = (float*)d_out;

  float* E1  = (float*)d_ws;                     // [B*L, D]        2 MB
  float* E2c = E1 + (size_t)BB * LL * DD;        // [D/4][B*T][4]   2 MB (4 MB)

  proj_gemm<<<dim3((BB * LL + BB * TT) / 32, DD / 64), 256, 0, stream>>>(
      x, mem, W1, b1, W2, b2, E1, E2c);
  fused_attn<<<512, 512, 0, stream>>>(
      E1, E2c, wt, mem, mask, outp);
}